// Round 1
// baseline (561.274 us; speedup 1.0000x reference)
//
#include <hip/hip_runtime.h>
#include <stdint.h>

#define B_ 4
#define S_ 2048
#define HID_ 1024
#define NH_ 16
#define HD_ 64

typedef __bf16 bf16x8 __attribute__((ext_vector_type(8)));
typedef __bf16 bf16x4 __attribute__((ext_vector_type(4)));
typedef float f32x4 __attribute__((ext_vector_type(4)));

__device__ inline void gload_lds16(const void* g, void* l) {
  __builtin_amdgcn_global_load_lds((const __attribute__((address_space(1))) unsigned int*)g,
                                   (__attribute__((address_space(3))) unsigned int*)l, 16, 0, 0);
}

// ---------------- fp32 -> bf16 conversion (4 elems/thread, exact grid) ----------------
__global__ __launch_bounds__(256) void cvt_bf16(const float* __restrict__ in, __bf16* __restrict__ out) {
  int i = (blockIdx.x * 256 + threadIdx.x) * 4;
  f32x4 v = *(const f32x4*)(in + i);
  bf16x4 o;
  o[0] = (__bf16)v[0]; o[1] = (__bf16)v[1]; o[2] = (__bf16)v[2]; o[3] = (__bf16)v[3];
  *(bf16x4*)(out + i) = o;
}

// ---------------- GEMM: C[M,N] = A[M,K] * Bt[N,K]^T (+bias), bf16 inputs ----------------
// 128x128 tile, BK=64, 4 waves (2x2), per-wave 64x64 = 4x4 frags of 16x16, MFMA 16x16x32.
template <typename OUT_T, bool HAS_BIAS>
__global__ __launch_bounds__(256) void gemm_bt(const __bf16* __restrict__ A,
                                               const __bf16* __restrict__ Bt,
                                               const float* __restrict__ bias,
                                               OUT_T* __restrict__ C,
                                               int M, int N, int K) {
  const int n0 = blockIdx.x * 128;
  const int m0 = blockIdx.y * 128;
  const int tid  = threadIdx.x;
  const int wave = tid >> 6, lane = tid & 63;
  const int wm = wave >> 1, wn = wave & 1;
  const int lrow = lane & 15, lgrp = lane >> 4;

  __shared__ __bf16 sA[128][64];
  __shared__ __bf16 sB[128][64];

  f32x4 acc[4][4];
#pragma unroll
  for (int i = 0; i < 4; i++)
#pragma unroll
    for (int j = 0; j < 4; j++) acc[i][j] = f32x4{0.f, 0.f, 0.f, 0.f};

  for (int k0 = 0; k0 < K; k0 += 64) {
    __syncthreads();
#pragma unroll
    for (int c = 0; c < 4; c++) {
      const int row = wave * 32 + c * 8;  // wave-uniform LDS base row
      const __bf16* ga = A + (size_t)(m0 + row + (lane >> 3)) * K + k0 + (lane & 7) * 8;
      gload_lds16(ga, &sA[row][0]);
      const __bf16* gb = Bt + (size_t)(n0 + row + (lane >> 3)) * K + k0 + (lane & 7) * 8;
      gload_lds16(gb, &sB[row][0]);
    }
    __syncthreads();
#pragma unroll
    for (int kk = 0; kk < 2; kk++) {
      bf16x8 af[4], bfr[4];
#pragma unroll
      for (int i = 0; i < 4; i++) {
        af[i]  = *(const bf16x8*)(&sA[wm * 64 + i * 16 + lrow][kk * 32 + 8 * lgrp]);
        bfr[i] = *(const bf16x8*)(&sB[wn * 64 + i * 16 + lrow][kk * 32 + 8 * lgrp]);
      }
#pragma unroll
      for (int i = 0; i < 4; i++)
#pragma unroll
        for (int j = 0; j < 4; j++)
          acc[i][j] = __builtin_amdgcn_mfma_f32_16x16x32_bf16(af[i], bfr[j], acc[i][j], 0, 0, 0);
    }
  }

#pragma unroll
  for (int i = 0; i < 4; i++) {
#pragma unroll
    for (int j = 0; j < 4; j++) {
      const int n = n0 + wn * 64 + j * 16 + lrow;
      float bv = 0.f;
      if (HAS_BIAS) bv = bias[n];
#pragma unroll
      for (int r = 0; r < 4; r++) {
        const int m = m0 + wm * 64 + i * 16 + lgrp * 4 + r;
        C[(size_t)m * N + n] = (OUT_T)(acc[i][j][r] + bv);
      }
    }
  }
}

// ---------------- qk-norm: one wave per (b*s, h) row of 64, in-place ----------------
__global__ __launch_bounds__(256) void qknorm(__bf16* __restrict__ t, const float* __restrict__ gamma,
                                              int row_stride) {
  const int wid  = blockIdx.x * 4 + (threadIdx.x >> 6);  // 0 .. B*S*NH-1
  const int lane = threadIdx.x & 63;
  const int bs = wid >> 4, h = wid & 15;
  __bf16* p = t + (size_t)bs * row_stride + h * HD_ + lane;
  float v = (float)*p;
  float ss = v * v;
#pragma unroll
  for (int off = 1; off < 64; off <<= 1) ss += __shfl_xor(ss, off, 64);
  const float nrm = sqrtf(ss);
  const float sc = 8.f * gamma[h * HD_ + lane] / fmaxf(nrm, 1e-12f);
  *p = (__bf16)(v * sc);
}

// ---------------- flash attention ----------------
// grid (S/64, B*NH), 4 waves; wave handles 16 q-rows; KV tiles of 64.
__global__ __launch_bounds__(256) void attn_kernel(const __bf16* __restrict__ q,   // [B,S,NH*HD] normalized
                                                   const __bf16* __restrict__ kv,  // [B,S,2*HID] (k normalized)
                                                   __bf16* __restrict__ o) {       // [B,S,NH*HD]
  const int q0 = blockIdx.x * 64;
  const int bh = blockIdx.y;
  const int b = bh >> 4, h = bh & 15;
  const int tid  = threadIdx.x;
  const int wave = tid >> 6, lane = tid & 63;
  const int lrow = lane & 15, lgrp = lane >> 4;

  __shared__ __bf16 sK[64][64];   // [kv, d]   xor-swizzled
  __shared__ __bf16 sVt[64][64];  // [d, kv]   xor-swizzled
  __shared__ __bf16 sP[4][16][64];

  // Q fragments in registers: rows q0 + wave*16 + lrow, k-dim = d
  const __bf16* qbase = q + (size_t)(b * S_ + q0 + wave * 16 + lrow) * HID_ + h * HD_;
  bf16x8 qf[2];
  qf[0] = *(const bf16x8*)(qbase + 8 * lgrp);
  qf[1] = *(const bf16x8*)(qbase + 32 + 8 * lgrp);

  f32x4 accd[4];
#pragma unroll
  for (int i = 0; i < 4; i++) accd[i] = f32x4{0.f, 0.f, 0.f, 0.f};
  float m_r[4], l_r[4];
#pragma unroll
  for (int j = 0; j < 4; j++) { m_r[j] = -1e30f; l_r[j] = 0.f; }

  const __bf16* kvb = kv + (size_t)(b * S_) * 2048 + h * HD_;  // k at +0, v at +1024; row stride 2048

  for (int kt = 0; kt < S_ / 64; ++kt) {
    __syncthreads();
    // stage K and V^T tiles (512 chunks of 8 elems each)
#pragma unroll
    for (int c = 0; c < 2; ++c) {
      const int chunk = tid + c * 256;
      const int row = chunk >> 3;           // kv row within tile
      const int col = (chunk & 7) * 8;      // d
      const __bf16* gsrc = kvb + (size_t)(kt * 64 + row) * 2048 + col;
      bf16x8 kvv = *(const bf16x8*)(gsrc);
      *(bf16x8*)(&sK[row][col ^ ((row & 7) << 3)]) = kvv;
      bf16x8 vv = *(const bf16x8*)(gsrc + 1024);
#pragma unroll
      for (int j = 0; j < 8; j++) {
        const int d = col + j;
        sVt[d][row ^ ((d & 7) << 3)] = vv[j];
      }
    }
    __syncthreads();

    // QK^T: 4 col-tiles of 16 kv
    f32x4 sc[4];
#pragma unroll
    for (int t = 0; t < 4; t++) {
      sc[t] = f32x4{0.f, 0.f, 0.f, 0.f};
#pragma unroll
      for (int kk = 0; kk < 2; kk++) {
        const int krow = t * 16 + lrow;
        const int c0 = kk * 32 + 8 * lgrp;
        bf16x8 kf = *(const bf16x8*)(&sK[krow][c0 ^ ((krow & 7) << 3)]);
        sc[t] = __builtin_amdgcn_mfma_f32_16x16x32_bf16(qf[kk], kf, sc[t], 0, 0, 0);
      }
    }

    // online softmax (rows = lgrp*4+j, cols spread over 16 lanes)
    float tmax[4];
#pragma unroll
    for (int j = 0; j < 4; j++)
      tmax[j] = fmaxf(fmaxf(sc[0][j], sc[1][j]), fmaxf(sc[2][j], sc[3][j]));
#pragma unroll
    for (int off = 1; off < 16; off <<= 1)
#pragma unroll
      for (int j = 0; j < 4; j++) tmax[j] = fmaxf(tmax[j], __shfl_xor(tmax[j], off, 64));

    float scl[4];
#pragma unroll
    for (int j = 0; j < 4; j++) {
      const float mn = fmaxf(m_r[j], tmax[j]);
      scl[j] = __expf(m_r[j] - mn);
      m_r[j] = mn;
      l_r[j] *= scl[j];
    }
#pragma unroll
    for (int i = 0; i < 4; i++)
#pragma unroll
      for (int j = 0; j < 4; j++) accd[i][j] *= scl[j];

    float psum[4] = {0.f, 0.f, 0.f, 0.f};
#pragma unroll
    for (int t = 0; t < 4; t++) {
#pragma unroll
      for (int j = 0; j < 4; j++) {
        const float p = __expf(sc[t][j] - m_r[j]);
        psum[j] += p;
        const int pr = lgrp * 4 + j;
        const int pc = t * 16 + lrow;
        sP[wave][pr][pc ^ ((pr & 7) << 3)] = (__bf16)p;
      }
    }
#pragma unroll
    for (int off = 1; off < 16; off <<= 1)
#pragma unroll
      for (int j = 0; j < 4; j++) psum[j] += __shfl_xor(psum[j], off, 64);
#pragma unroll
    for (int j = 0; j < 4; j++) l_r[j] += psum[j];

    // PV: acc[dt] += P(16x32) * V(32x16) for each 16-wide d-tile, 2 k-halves
#pragma unroll
    for (int half = 0; half < 2; ++half) {
      const int pc0 = half * 32 + 8 * lgrp;
      bf16x8 pf = *(const bf16x8*)(&sP[wave][lrow][pc0 ^ ((lrow & 7) << 3)]);
#pragma unroll
      for (int dt = 0; dt < 4; ++dt) {
        const int d = dt * 16 + lrow;
        bf16x8 vf = *(const bf16x8*)(&sVt[d][pc0 ^ ((d & 7) << 3)]);
        accd[dt] = __builtin_amdgcn_mfma_f32_16x16x32_bf16(pf, vf, accd[dt], 0, 0, 0);
      }
    }
  }

  // epilogue: divide by l, store bf16
#pragma unroll
  for (int j = 0; j < 4; j++) {
    const int qi = lgrp * 4 + j;
    const float inv = 1.f / l_r[j];
    __bf16* ob = o + (size_t)(b * S_ + q0 + wave * 16 + qi) * HID_ + h * HD_;
#pragma unroll
    for (int dt = 0; dt < 4; dt++) ob[dt * 16 + lrow] = (__bf16)(accd[dt][j] * inv);
  }
}

extern "C" void kernel_launch(void* const* d_in, const int* in_sizes, int n_in,
                              void* d_out, int out_size, void* d_ws, size_t ws_size,
                              hipStream_t stream) {
  (void)in_sizes; (void)n_in; (void)out_size; (void)ws_size;
  const float* x       = (const float*)d_in[0];
  const float* q_w     = (const float*)d_in[1];
  const float* q_b     = (const float*)d_in[2];
  const float* kv_w    = (const float*)d_in[3];
  const float* kv_b    = (const float*)d_in[4];
  const float* gamma_q = (const float*)d_in[5];
  const float* gamma_k = (const float*)d_in[6];
  const float* out_w   = (const float*)d_in[7];
  float* out = (float*)d_out;

  char* ws = (char*)d_ws;
  __bf16* x_bf   = (__bf16*)(ws);                        // 16 MB: [8192,1024]
  __bf16* qw_bf  = (__bf16*)(ws + (16ull << 20));        // 2 MB
  __bf16* kvw_bf = (__bf16*)(ws + (18ull << 20));        // 4 MB
  __bf16* ow_bf  = (__bf16*)(ws + (22ull << 20));        // 2 MB
  __bf16* q_bf   = (__bf16*)(ws + (24ull << 20));        // 16 MB: [8192,1024]
  __bf16* kv_bf  = (__bf16*)(ws + (40ull << 20));        // 32 MB: [8192,2048]
  __bf16* at_bf  = (__bf16*)(ws + (72ull << 20));        // 16 MB: [8192,1024]

  cvt_bf16<<<8192, 256, 0, stream>>>(x, x_bf);
  cvt_bf16<<<1024, 256, 0, stream>>>(q_w, qw_bf);
  cvt_bf16<<<2048, 256, 0, stream>>>(kv_w, kvw_bf);
  cvt_bf16<<<1024, 256, 0, stream>>>(out_w, ow_bf);

  gemm_bt<__bf16, true><<<dim3(8, 64), 256, 0, stream>>>(x_bf, qw_bf, q_b, q_bf, 8192, 1024, 1024);
  gemm_bt<__bf16, true><<<dim3(16, 64), 256, 0, stream>>>(x_bf, kvw_bf, kv_b, kv_bf, 8192, 2048, 1024);

  qknorm<<<32768, 256, 0, stream>>>(q_bf, gamma_q, 1024);
  qknorm<<<32768, 256, 0, stream>>>(kv_bf, gamma_k, 2048);

  attn_kernel<<<dim3(32, 64), 256, 0, stream>>>(q_bf, kv_bf, at_bf);

  gemm_bt<float, false><<<dim3(8, 64), 256, 0, stream>>>(at_bf, ow_bf, nullptr, out, 8192, 1024, 1024);
}

// Round 2
// 452.353 us; speedup vs baseline: 1.2408x; 1.2408x over previous
//
#include <hip/hip_runtime.h>
#include <stdint.h>

#define B_ 4
#define S_ 2048
#define HID_ 1024
#define NH_ 16
#define HD_ 64

typedef __bf16 bf16x8 __attribute__((ext_vector_type(8)));
typedef __bf16 bf16x4 __attribute__((ext_vector_type(4)));
typedef float f32x4 __attribute__((ext_vector_type(4)));

__device__ inline void gload_lds16(const void* g, void* l) {
  __builtin_amdgcn_global_load_lds((const __attribute__((address_space(1))) unsigned int*)g,
                                   (__attribute__((address_space(3))) unsigned int*)l, 16, 0, 0);
}

// ---------------- fp32 -> bf16 conversion ----------------
__global__ __launch_bounds__(256) void cvt_bf16(const float* __restrict__ in, __bf16* __restrict__ out) {
  int i = (blockIdx.x * 256 + threadIdx.x) * 4;
  f32x4 v = *(const f32x4*)(in + i);
  bf16x4 o;
  o[0] = (__bf16)v[0]; o[1] = (__bf16)v[1]; o[2] = (__bf16)v[2]; o[3] = (__bf16)v[3];
  *(bf16x4*)(out + i) = o;
}

// ---------------- GEMM: C[M,N] = A[M,K]*Bt[N,K]^T (+bias) with fused epilogues --------
// MODE 1: float out (no bias)          -> Cf[m*N+n]
// MODE 2: bias + qknorm, bf16 out      -> Cb[m*1024+n]          (q projection)
// MODE 3: kv: n<1024 bias+qknorm -> Cb (k); n>=1024 bias -> vt[B,H,D,S] transposed (v)
template <int MODE>
__global__ __launch_bounds__(256) void gemm_bt(const __bf16* __restrict__ A,
                                               const __bf16* __restrict__ Bt,
                                               const float* __restrict__ bias,
                                               const float* __restrict__ gamma,
                                               __bf16* __restrict__ Cb,
                                               float* __restrict__ Cf,
                                               __bf16* __restrict__ vt,
                                               int M, int N, int K) {
  const int n0 = blockIdx.x * 128;
  const int m0 = blockIdx.y * 128;
  const int tid  = threadIdx.x;
  const int wave = tid >> 6, lane = tid & 63;
  const int wm = wave >> 1, wn = wave & 1;
  const int lrow = lane & 15, lgrp = lane >> 4;

  __shared__ __bf16 sA[128][64];
  __shared__ __bf16 sB[128][64];

  f32x4 acc[4][4];
#pragma unroll
  for (int i = 0; i < 4; i++)
#pragma unroll
    for (int j = 0; j < 4; j++) acc[i][j] = f32x4{0.f, 0.f, 0.f, 0.f};

  for (int k0 = 0; k0 < K; k0 += 64) {
    __syncthreads();
#pragma unroll
    for (int c = 0; c < 4; c++) {
      const int row = wave * 32 + c * 8;
      const __bf16* ga = A + (size_t)(m0 + row + (lane >> 3)) * K + k0 + (lane & 7) * 8;
      gload_lds16(ga, &sA[row][0]);
      const __bf16* gb = Bt + (size_t)(n0 + row + (lane >> 3)) * K + k0 + (lane & 7) * 8;
      gload_lds16(gb, &sB[row][0]);
    }
    __syncthreads();
#pragma unroll
    for (int kk = 0; kk < 2; kk++) {
      bf16x8 af[4], bfr[4];
#pragma unroll
      for (int i = 0; i < 4; i++) {
        af[i]  = *(const bf16x8*)(&sA[wm * 64 + i * 16 + lrow][kk * 32 + 8 * lgrp]);
        bfr[i] = *(const bf16x8*)(&sB[wn * 64 + i * 16 + lrow][kk * 32 + 8 * lgrp]);
      }
#pragma unroll
      for (int i = 0; i < 4; i++)
#pragma unroll
        for (int j = 0; j < 4; j++)
          acc[i][j] = __builtin_amdgcn_mfma_f32_16x16x32_bf16(af[i], bfr[j], acc[i][j], 0, 0, 0);
    }
  }

  // ---- epilogue ----
  if (MODE != 1) {
    float bv[4];
#pragma unroll
    for (int j = 0; j < 4; j++) bv[j] = bias[n0 + wn * 64 + j * 16 + lrow];
#pragma unroll
    for (int i = 0; i < 4; i++)
#pragma unroll
      for (int j = 0; j < 4; j++)
#pragma unroll
        for (int r = 0; r < 4; r++) acc[i][j][r] += bv[j];
  }

  const bool do_norm = (MODE == 2) || (MODE == 3 && n0 < 1024);
  if (do_norm) {
    float g[4];
#pragma unroll
    for (int j = 0; j < 4; j++) g[j] = gamma[(n0 + wn * 64 + j * 16 + lrow) & 1023];
#pragma unroll
    for (int i = 0; i < 4; i++) {
#pragma unroll
      for (int r = 0; r < 4; r++) {
        float ss = acc[i][0][r] * acc[i][0][r] + acc[i][1][r] * acc[i][1][r] +
                   acc[i][2][r] * acc[i][2][r] + acc[i][3][r] * acc[i][3][r];
#pragma unroll
        for (int off = 1; off < 16; off <<= 1) ss += __shfl_xor(ss, off, 64);
        const float inv = 8.f / fmaxf(sqrtf(ss), 1e-12f);
        const int m = m0 + wm * 64 + i * 16 + lgrp * 4 + r;
#pragma unroll
        for (int j = 0; j < 4; j++) {
          const int n = (n0 + wn * 64 + j * 16 + lrow) & 1023;
          Cb[(size_t)m * 1024 + n] = (__bf16)(acc[i][j][r] * inv * g[j]);
        }
      }
    }
  } else if (MODE == 3) {
    // v half: write transposed vt[b][h][d][s], packed 4 consecutive s per store
#pragma unroll
    for (int i = 0; i < 4; i++) {
#pragma unroll
      for (int j = 0; j < 4; j++) {
        const int nn = n0 + wn * 64 + j * 16 + lrow - 1024;
        const int h = nn >> 6, d = nn & 63;
        const int m = m0 + wm * 64 + i * 16 + lgrp * 4;
        const int b = m >> 11, s0 = m & 2047;
        bf16x4 pk;
#pragma unroll
        for (int r = 0; r < 4; r++) pk[r] = (__bf16)acc[i][j][r];
        *(bf16x4*)(vt + ((size_t)((b * 16 + h) * 64 + d)) * 2048 + s0) = pk;
      }
    }
  } else {  // MODE 1
#pragma unroll
    for (int i = 0; i < 4; i++)
#pragma unroll
      for (int j = 0; j < 4; j++) {
        const int n = n0 + wn * 64 + j * 16 + lrow;
#pragma unroll
        for (int r = 0; r < 4; r++) {
          const int m = m0 + wm * 64 + i * 16 + lgrp * 4 + r;
          Cf[(size_t)m * N + n] = acc[i][j][r];
        }
      }
  }
}

// ---------------- flash attention ----------------
// grid (16, 64) XCD-swizzled; 4 waves; wave owns 32 q-rows (2 row-tiles of 16); KV tiles 64.
// K staged [kv][d], Vt staged [d][kv], both via global_load_lds with pre-swizzled source
// (read swizzle: chunk ^= row&7, i.e. byte ^= (row&7)<<4).
__global__ __launch_bounds__(256) void attn_kernel(const __bf16* __restrict__ qm,
                                                   const __bf16* __restrict__ km,
                                                   const __bf16* __restrict__ vtm,
                                                   __bf16* __restrict__ o) {
  const int lin = blockIdx.y * gridDim.x + blockIdx.x;  // 1024 blocks
  const int swz = (lin & 7) * 128 + (lin >> 3);         // bijective, groups bh per XCD
  const int qb = swz & 15;
  const int bh = swz >> 4;
  const int b = bh >> 4, h = bh & 15;
  const int q0 = qb * 128;
  const int tid = threadIdx.x, wave = tid >> 6, lane = tid & 63;
  const int lrow = lane & 15, lgrp = lane >> 4;

  __shared__ __bf16 sK[2][64 * 64];
  __shared__ __bf16 sVt[2][64 * 64];
  __shared__ __bf16 sP[4][16 * 64];

  const __bf16* kbase  = km + (size_t)(b * S_) * 1024 + h * 64;
  const __bf16* vtbase = vtm + (size_t)((b * 16 + h) * 64) * 2048;

  const int srow = lane >> 3;   // 0..7
  const int pchunk = lane & 7;  // physical 16B chunk within 128B row

  auto stage = [&](int buf, int kt) {
#pragma unroll
    for (int i8 = 0; i8 < 2; ++i8) {
      const int rr = wave * 16 + i8 * 8;   // wave-uniform base row
      const int r = rr + srow;             // per-lane row (kv for K, d for Vt)
      gload_lds16(kbase + (size_t)(kt * 64 + r) * 1024 + ((pchunk ^ (r & 7)) << 3),
                  &sK[buf][rr * 64]);
      gload_lds16(vtbase + (size_t)r * 2048 + kt * 64 + ((pchunk ^ (r & 7)) << 3),
                  &sVt[buf][rr * 64]);
    }
  };

  // Q fragments in registers (2 row-tiles x 2 k-halves)
  bf16x8 qf[2][2];
#pragma unroll
  for (int rt = 0; rt < 2; ++rt) {
    const __bf16* qp = qm + (size_t)(b * S_ + q0 + wave * 32 + rt * 16 + lrow) * 1024 + h * 64;
    qf[rt][0] = *(const bf16x8*)(qp + 8 * lgrp);
    qf[rt][1] = *(const bf16x8*)(qp + 32 + 8 * lgrp);
  }

  f32x4 accd[2][4];
#pragma unroll
  for (int rt = 0; rt < 2; ++rt)
#pragma unroll
    for (int dt = 0; dt < 4; ++dt) accd[rt][dt] = f32x4{0.f, 0.f, 0.f, 0.f};
  float m_r[2][4], l_r[2][4];
#pragma unroll
  for (int rt = 0; rt < 2; ++rt)
#pragma unroll
    for (int j = 0; j < 4; ++j) { m_r[rt][j] = -1e30f; l_r[rt][j] = 0.f; }

  stage(0, 0);
  int buf = 0;
  for (int kt = 0; kt < S_ / 64; ++kt) {
    __syncthreads();                       // drains vmcnt: tile kt ready
    if (kt + 1 < S_ / 64) stage(buf ^ 1, kt + 1);

    // QK^T: K fragments shared by both row-tiles
    f32x4 sc[2][4];
#pragma unroll
    for (int rt = 0; rt < 2; ++rt)
#pragma unroll
      for (int t = 0; t < 4; ++t) sc[rt][t] = f32x4{0.f, 0.f, 0.f, 0.f};
#pragma unroll
    for (int t = 0; t < 4; ++t) {
      const int krow = t * 16 + lrow;
#pragma unroll
      for (int kk = 0; kk < 2; ++kk) {
        bf16x8 kf = *(const bf16x8*)(&sK[buf][krow * 64 + (((kk * 4 + lgrp) ^ (krow & 7)) << 3)]);
        sc[0][t] = __builtin_amdgcn_mfma_f32_16x16x32_bf16(qf[0][kk], kf, sc[0][t], 0, 0, 0);
        sc[1][t] = __builtin_amdgcn_mfma_f32_16x16x32_bf16(qf[1][kk], kf, sc[1][t], 0, 0, 0);
      }
    }

#pragma unroll
    for (int rt = 0; rt < 2; ++rt) {
      float tmax[4], scl[4], psum[4];
#pragma unroll
      for (int j = 0; j < 4; ++j)
        tmax[j] = fmaxf(fmaxf(sc[rt][0][j], sc[rt][1][j]), fmaxf(sc[rt][2][j], sc[rt][3][j]));
#pragma unroll
      for (int off = 1; off < 16; off <<= 1)
#pragma unroll
        for (int j = 0; j < 4; ++j) tmax[j] = fmaxf(tmax[j], __shfl_xor(tmax[j], off, 64));
#pragma unroll
      for (int j = 0; j < 4; ++j) {
        const float mn = fmaxf(m_r[rt][j], tmax[j]);
        scl[j] = __expf(m_r[rt][j] - mn);
        m_r[rt][j] = mn;
        l_r[rt][j] *= scl[j];
        psum[j] = 0.f;
      }
#pragma unroll
      for (int dt = 0; dt < 4; ++dt)
#pragma unroll
        for (int j = 0; j < 4; ++j) accd[rt][dt][j] *= scl[j];

      // exp + write P (swizzled scalar writes, 2-way max conflicts)
#pragma unroll
      for (int t = 0; t < 4; ++t) {
#pragma unroll
        for (int j = 0; j < 4; ++j) {
          const float p = __expf(sc[rt][t][j] - m_r[rt][j]);
          psum[j] += p;
          const int pr = lgrp * 4 + j;
          sP[wave][pr * 64 + (((t * 2 + (lrow >> 3)) ^ (pr & 7)) << 3) + (lrow & 7)] = (__bf16)p;
        }
      }
#pragma unroll
      for (int off = 1; off < 16; off <<= 1)
#pragma unroll
        for (int j = 0; j < 4; ++j) psum[j] += __shfl_xor(psum[j], off, 64);
#pragma unroll
      for (int j = 0; j < 4; ++j) l_r[rt][j] += psum[j];

      // PV
#pragma unroll
      for (int half = 0; half < 2; ++half) {
        bf16x8 pf = *(const bf16x8*)(&sP[wave][lrow * 64 + (((half * 4 + lgrp) ^ (lrow & 7)) << 3)]);
#pragma unroll
        for (int dt = 0; dt < 4; ++dt) {
          const int d = dt * 16 + lrow;
          bf16x8 vf = *(const bf16x8*)(&sVt[buf][d * 64 + (((half * 4 + lgrp) ^ (d & 7)) << 3)]);
          accd[rt][dt] = __builtin_amdgcn_mfma_f32_16x16x32_bf16(pf, vf, accd[rt][dt], 0, 0, 0);
        }
      }
    }
    buf ^= 1;
  }

  // epilogue
#pragma unroll
  for (int rt = 0; rt < 2; ++rt)
#pragma unroll
    for (int j = 0; j < 4; ++j) {
      const float inv = 1.f / l_r[rt][j];
      const int row = b * S_ + q0 + wave * 32 + rt * 16 + lgrp * 4 + j;
      __bf16* ob = o + (size_t)row * 1024 + h * 64;
#pragma unroll
      for (int dt = 0; dt < 4; ++dt) ob[dt * 16 + lrow] = (__bf16)(accd[rt][dt][j] * inv);
    }
}

extern "C" void kernel_launch(void* const* d_in, const int* in_sizes, int n_in,
                              void* d_out, int out_size, void* d_ws, size_t ws_size,
                              hipStream_t stream) {
  (void)in_sizes; (void)n_in; (void)out_size; (void)ws_size;
  const float* x       = (const float*)d_in[0];
  const float* q_w     = (const float*)d_in[1];
  const float* q_b     = (const float*)d_in[2];
  const float* kv_w    = (const float*)d_in[3];
  const float* kv_b    = (const float*)d_in[4];
  const float* gamma_q = (const float*)d_in[5];
  const float* gamma_k = (const float*)d_in[6];
  const float* out_w   = (const float*)d_in[7];
  float* out = (float*)d_out;

  char* ws = (char*)d_ws;
  __bf16* x_bf   = (__bf16*)(ws);                  // 16 MB [8192,1024]
  __bf16* qw_bf  = (__bf16*)(ws + (16ull << 20));  // 2 MB
  __bf16* kvw_bf = (__bf16*)(ws + (18ull << 20));  // 4 MB
  __bf16* ow_bf  = (__bf16*)(ws + (22ull << 20));  // 2 MB
  __bf16* q_bf   = (__bf16*)(ws + (24ull << 20));  // 16 MB [8192,1024] normalized q
  __bf16* k_bf   = (__bf16*)(ws + (40ull << 20));  // 16 MB [8192,1024] normalized k
  __bf16* vt_bf  = (__bf16*)(ws + (56ull << 20));  // 16 MB [B,H,D,S]
  __bf16* at_bf  = (__bf16*)(ws + (72ull << 20));  // 16 MB [8192,1024]

  cvt_bf16<<<8192, 256, 0, stream>>>(x, x_bf);
  cvt_bf16<<<1024, 256, 0, stream>>>(q_w, qw_bf);
  cvt_bf16<<<2048, 256, 0, stream>>>(kv_w, kvw_bf);
  cvt_bf16<<<1024, 256, 0, stream>>>(out_w, ow_bf);

  gemm_bt<2><<<dim3(8, 64), 256, 0, stream>>>(x_bf, qw_bf, q_b, gamma_q, q_bf, nullptr, nullptr,
                                              8192, 1024, 1024);
  gemm_bt<3><<<dim3(16, 64), 256, 0, stream>>>(x_bf, kvw_bf, kv_b, gamma_k, k_bf, nullptr, vt_bf,
                                               8192, 2048, 1024);

  attn_kernel<<<dim3(16, 64), 256, 0, stream>>>(q_bf, k_bf, vt_bf, at_bf);

  gemm_bt<1><<<dim3(8, 64), 256, 0, stream>>>(at_bf, ow_bf, nullptr, nullptr, nullptr, out, nullptr,
                                              8192, 1024, 1024);
}

// Round 3
// 370.482 us; speedup vs baseline: 1.5150x; 1.2210x over previous
//
#include <hip/hip_runtime.h>
#include <stdint.h>

#define B_ 4
#define S_ 2048
#define HID_ 1024
#define NH_ 16
#define HD_ 64

typedef __bf16 bf16x8 __attribute__((ext_vector_type(8)));
typedef __bf16 bf16x4 __attribute__((ext_vector_type(4)));
typedef float f32x4 __attribute__((ext_vector_type(4)));

__device__ inline void gload_lds16(const void* g, void* l) {
  __builtin_amdgcn_global_load_lds((const __attribute__((address_space(1))) unsigned int*)g,
                                   (__attribute__((address_space(3))) unsigned int*)l, 16, 0, 0);
}

__device__ inline f32x4 fmax4(f32x4 a, f32x4 b) {
  f32x4 r;
  r[0] = fmaxf(a[0], b[0]); r[1] = fmaxf(a[1], b[1]);
  r[2] = fmaxf(a[2], b[2]); r[3] = fmaxf(a[3], b[3]);
  return r;
}

// ---------------- fp32 -> bf16 conversion ----------------
__global__ __launch_bounds__(256) void cvt_bf16(const float* __restrict__ in, __bf16* __restrict__ out) {
  int i = (blockIdx.x * 256 + threadIdx.x) * 4;
  f32x4 v = *(const f32x4*)(in + i);
  bf16x4 o;
  o[0] = (__bf16)v[0]; o[1] = (__bf16)v[1]; o[2] = (__bf16)v[2]; o[3] = (__bf16)v[3];
  *(bf16x4*)(out + i) = o;
}

// ---------------- GEMM: C[M,N] = A[M,K]*Bt[N,K]^T (+bias) with fused epilogues --------
// MODE 1: float out (no bias)          -> Cf[m*N+n]
// MODE 2: bias + qknorm, bf16 out      -> Cb[m*1024+n]          (q projection)
// MODE 3: kv: n<1024 bias+qknorm -> Cb (k); n>=1024 bias -> vt[B,H,D,S] transposed (v)
template <int MODE>
__global__ __launch_bounds__(256) void gemm_bt(const __bf16* __restrict__ A,
                                               const __bf16* __restrict__ Bt,
                                               const float* __restrict__ bias,
                                               const float* __restrict__ gamma,
                                               __bf16* __restrict__ Cb,
                                               float* __restrict__ Cf,
                                               __bf16* __restrict__ vt,
                                               int M, int N, int K) {
  const int n0 = blockIdx.x * 128;
  const int m0 = blockIdx.y * 128;
  const int tid  = threadIdx.x;
  const int wave = tid >> 6, lane = tid & 63;
  const int wm = wave >> 1, wn = wave & 1;
  const int lrow = lane & 15, lgrp = lane >> 4;

  __shared__ __bf16 sA[128][64];
  __shared__ __bf16 sB[128][64];

  f32x4 acc[4][4];
#pragma unroll
  for (int i = 0; i < 4; i++)
#pragma unroll
    for (int j = 0; j < 4; j++) acc[i][j] = f32x4{0.f, 0.f, 0.f, 0.f};

  for (int k0 = 0; k0 < K; k0 += 64) {
    __syncthreads();
#pragma unroll
    for (int c = 0; c < 4; c++) {
      const int row = wave * 32 + c * 8;
      const __bf16* ga = A + (size_t)(m0 + row + (lane >> 3)) * K + k0 + (lane & 7) * 8;
      gload_lds16(ga, &sA[row][0]);
      const __bf16* gb = Bt + (size_t)(n0 + row + (lane >> 3)) * K + k0 + (lane & 7) * 8;
      gload_lds16(gb, &sB[row][0]);
    }
    __syncthreads();
#pragma unroll
    for (int kk = 0; kk < 2; kk++) {
      bf16x8 af[4], bfr[4];
#pragma unroll
      for (int i = 0; i < 4; i++) {
        af[i]  = *(const bf16x8*)(&sA[wm * 64 + i * 16 + lrow][kk * 32 + 8 * lgrp]);
        bfr[i] = *(const bf16x8*)(&sB[wn * 64 + i * 16 + lrow][kk * 32 + 8 * lgrp]);
      }
#pragma unroll
      for (int i = 0; i < 4; i++)
#pragma unroll
        for (int j = 0; j < 4; j++)
          acc[i][j] = __builtin_amdgcn_mfma_f32_16x16x32_bf16(af[i], bfr[j], acc[i][j], 0, 0, 0);
    }
  }

  // ---- epilogue ----
  if (MODE != 1) {
    float bv[4];
#pragma unroll
    for (int j = 0; j < 4; j++) bv[j] = bias[n0 + wn * 64 + j * 16 + lrow];
#pragma unroll
    for (int i = 0; i < 4; i++)
#pragma unroll
      for (int j = 0; j < 4; j++)
#pragma unroll
        for (int r = 0; r < 4; r++) acc[i][j][r] += bv[j];
  }

  const bool do_norm = (MODE == 2) || (MODE == 3 && n0 < 1024);
  if (do_norm) {
    float g[4];
#pragma unroll
    for (int j = 0; j < 4; j++) g[j] = gamma[(n0 + wn * 64 + j * 16 + lrow) & 1023];
#pragma unroll
    for (int i = 0; i < 4; i++) {
#pragma unroll
      for (int r = 0; r < 4; r++) {
        float ss = acc[i][0][r] * acc[i][0][r] + acc[i][1][r] * acc[i][1][r] +
                   acc[i][2][r] * acc[i][2][r] + acc[i][3][r] * acc[i][3][r];
#pragma unroll
        for (int off = 1; off < 16; off <<= 1) ss += __shfl_xor(ss, off, 64);
        const float inv = 8.f / fmaxf(sqrtf(ss), 1e-12f);
        const int m = m0 + wm * 64 + i * 16 + lgrp * 4 + r;
#pragma unroll
        for (int j = 0; j < 4; j++) {
          const int n = (n0 + wn * 64 + j * 16 + lrow) & 1023;
          Cb[(size_t)m * 1024 + n] = (__bf16)(acc[i][j][r] * inv * g[j]);
        }
      }
    }
  } else if (MODE == 3) {
    // v half: write transposed vt[b][h][d][s], packed 4 consecutive s per store
#pragma unroll
    for (int i = 0; i < 4; i++) {
#pragma unroll
      for (int j = 0; j < 4; j++) {
        const int nn = n0 + wn * 64 + j * 16 + lrow - 1024;
        const int h = nn >> 6, d = nn & 63;
        const int m = m0 + wm * 64 + i * 16 + lgrp * 4;
        const int b = m >> 11, s0 = m & 2047;
        bf16x4 pk;
#pragma unroll
        for (int r = 0; r < 4; r++) pk[r] = (__bf16)acc[i][j][r];
        *(bf16x4*)(vt + ((size_t)((b * 16 + h) * 64 + d)) * 2048 + s0) = pk;
      }
    }
  } else {  // MODE 1
#pragma unroll
    for (int i = 0; i < 4; i++)
#pragma unroll
      for (int j = 0; j < 4; j++) {
        const int n = n0 + wn * 64 + j * 16 + lrow;
#pragma unroll
        for (int r = 0; r < 4; r++) {
          const int m = m0 + wm * 64 + i * 16 + lgrp * 4 + r;
          Cf[(size_t)m * N + n] = acc[i][j][r];
        }
      }
  }
}

// ---------------- flash attention (swapped QK^T: P rows lane-local) ----------------
// grid (16, 64) XCD-swizzled; 4 waves; wave owns 32 q-rows (2 row-tiles of 16); KV tiles 64.
// QK^T computes mfma(K, Q) so C = [kv][q]: lane holds q = lane&15, kv = t*16 + lgrp*4 + r.
// Row softmax: 15 in-lane max/add + 2 shfl_xor. P packed bf16x4 -> 4 ds_write_b64 per rt.
__global__ __launch_bounds__(256) void attn_kernel(const __bf16* __restrict__ qm,
                                                   const __bf16* __restrict__ km,
                                                   const __bf16* __restrict__ vtm,
                                                   __bf16* __restrict__ o) {
  const int lin = blockIdx.y * gridDim.x + blockIdx.x;  // 1024 blocks
  const int swz = (lin & 7) * 128 + (lin >> 3);         // bijective, groups bh per XCD
  const int qb = swz & 15;
  const int bh = swz >> 4;
  const int b = bh >> 4, h = bh & 15;
  const int q0 = qb * 128;
  const int tid = threadIdx.x, wave = tid >> 6, lane = tid & 63;
  const int lrow = lane & 15, lgrp = lane >> 4;

  __shared__ __bf16 sK[2][64 * 64];
  __shared__ __bf16 sVt[2][64 * 64];
  __shared__ __bf16 sP[4][16 * 64];

  const __bf16* kbase  = km + (size_t)(b * S_) * 1024 + h * 64;
  const __bf16* vtbase = vtm + (size_t)((b * 16 + h) * 64) * 2048;

  const int srow = lane >> 3;   // 0..7
  const int pchunk = lane & 7;  // physical 16B chunk within 128B row

  auto stage = [&](int buf, int kt) {
#pragma unroll
    for (int i8 = 0; i8 < 2; ++i8) {
      const int rr = wave * 16 + i8 * 8;   // wave-uniform base row
      const int r = rr + srow;             // per-lane row (kv for K, d for Vt)
      gload_lds16(kbase + (size_t)(kt * 64 + r) * 1024 + ((pchunk ^ (r & 7)) << 3),
                  &sK[buf][rr * 64]);
      gload_lds16(vtbase + (size_t)r * 2048 + kt * 64 + ((pchunk ^ (r & 7)) << 3),
                  &sVt[buf][rr * 64]);
    }
  };

  // Q fragments in registers (2 row-tiles x 2 k-halves)
  bf16x8 qf[2][2];
#pragma unroll
  for (int rt = 0; rt < 2; ++rt) {
    const __bf16* qp = qm + (size_t)(b * S_ + q0 + wave * 32 + rt * 16 + lrow) * 1024 + h * 64;
    qf[rt][0] = *(const bf16x8*)(qp + 8 * lgrp);
    qf[rt][1] = *(const bf16x8*)(qp + 32 + 8 * lgrp);
  }

  f32x4 accd[2][4];
#pragma unroll
  for (int rt = 0; rt < 2; ++rt)
#pragma unroll
    for (int dt = 0; dt < 4; ++dt) accd[rt][dt] = f32x4{0.f, 0.f, 0.f, 0.f};
  float m_r[2], l_r[2];
#pragma unroll
  for (int rt = 0; rt < 2; ++rt) { m_r[rt] = -1e30f; l_r[rt] = 0.f; }

  stage(0, 0);
  int buf = 0;
  for (int kt = 0; kt < S_ / 64; ++kt) {
    __syncthreads();                       // drains vmcnt: tile kt ready
    if (kt + 1 < S_ / 64) stage(buf ^ 1, kt + 1);

    // QK^T (swapped): sc[rt][t] = C[kv-block t][q], K fragments shared by both row-tiles
    f32x4 sc[2][4];
#pragma unroll
    for (int rt = 0; rt < 2; ++rt)
#pragma unroll
      for (int t = 0; t < 4; ++t) sc[rt][t] = f32x4{0.f, 0.f, 0.f, 0.f};
#pragma unroll
    for (int t = 0; t < 4; ++t) {
      const int krow = t * 16 + lrow;
#pragma unroll
      for (int kk = 0; kk < 2; ++kk) {
        bf16x8 kf = *(const bf16x8*)(&sK[buf][krow * 64 + (((kk * 4 + lgrp) ^ (krow & 7)) << 3)]);
        sc[0][t] = __builtin_amdgcn_mfma_f32_16x16x32_bf16(kf, qf[0][kk], sc[0][t], 0, 0, 0);
        sc[1][t] = __builtin_amdgcn_mfma_f32_16x16x32_bf16(kf, qf[1][kk], sc[1][t], 0, 0, 0);
      }
    }

#pragma unroll
    for (int rt = 0; rt < 2; ++rt) {
      // row max over 16 in-lane values + 2 shfl (replicas at lane^16, lane^32)
      f32x4 mm = fmax4(fmax4(sc[rt][0], sc[rt][1]), fmax4(sc[rt][2], sc[rt][3]));
      float tm = fmaxf(fmaxf(mm[0], mm[1]), fmaxf(mm[2], mm[3]));
      tm = fmaxf(tm, __shfl_xor(tm, 16, 64));
      tm = fmaxf(tm, __shfl_xor(tm, 32, 64));
      const float mn = fmaxf(m_r[rt], tm);
      const float scl = __expf(m_r[rt] - mn);
      m_r[rt] = mn;

      // exp, pack bf16x4, store P, partial sums
      float ps0 = 0.f, ps1 = 0.f;
#pragma unroll
      for (int t = 0; t < 4; ++t) {
        bf16x4 pk;
        float p0 = __expf(sc[rt][t][0] - mn);
        float p1 = __expf(sc[rt][t][1] - mn);
        float p2 = __expf(sc[rt][t][2] - mn);
        float p3 = __expf(sc[rt][t][3] - mn);
        ps0 += p0 + p2; ps1 += p1 + p3;
        pk[0] = (__bf16)p0; pk[1] = (__bf16)p1; pk[2] = (__bf16)p2; pk[3] = (__bf16)p3;
        // sP[wave][q=lrow][kv = t*16 + lgrp*4 .. +3], chunk-swizzled by (q&7)
        *(bf16x4*)(&sP[wave][lrow * 64 + (((2 * t + (lgrp >> 1)) ^ (lrow & 7)) << 3) +
                             ((lgrp & 1) << 2)]) = pk;
      }
      float ps = ps0 + ps1;
      ps += __shfl_xor(ps, 16, 64);
      ps += __shfl_xor(ps, 32, 64);
      l_r[rt] = l_r[rt] * scl + ps;

      // rescale accd (rows q = lgrp*4 + j); broadcast scl from lane holding that q
      float sclr[4];
#pragma unroll
      for (int j = 0; j < 4; ++j) sclr[j] = __shfl(scl, lgrp * 4 + j, 64);
#pragma unroll
      for (int dt = 0; dt < 4; ++dt)
#pragma unroll
        for (int j = 0; j < 4; ++j) accd[rt][dt][j] *= sclr[j];

      // PV
#pragma unroll
      for (int half = 0; half < 2; ++half) {
        bf16x8 pf = *(const bf16x8*)(&sP[wave][lrow * 64 + (((half * 4 + lgrp) ^ (lrow & 7)) << 3)]);
#pragma unroll
        for (int dt = 0; dt < 4; ++dt) {
          const int d = dt * 16 + lrow;
          bf16x8 vf = *(const bf16x8*)(&sVt[buf][d * 64 + (((half * 4 + lgrp) ^ (d & 7)) << 3)]);
          accd[rt][dt] = __builtin_amdgcn_mfma_f32_16x16x32_bf16(pf, vf, accd[rt][dt], 0, 0, 0);
        }
      }
    }
    buf ^= 1;
  }

  // epilogue: broadcast l from owner lanes, divide, store bf16
#pragma unroll
  for (int rt = 0; rt < 2; ++rt) {
#pragma unroll
    for (int j = 0; j < 4; ++j) {
      const float lv = __shfl(l_r[rt], lgrp * 4 + j, 64);
      const float inv = 1.f / lv;
      const int row = b * S_ + q0 + wave * 32 + rt * 16 + lgrp * 4 + j;
      __bf16* ob = o + (size_t)row * 1024 + h * 64;
#pragma unroll
      for (int dt = 0; dt < 4; ++dt) ob[dt * 16 + lrow] = (__bf16)(accd[rt][dt][j] * inv);
    }
  }
}

extern "C" void kernel_launch(void* const* d_in, const int* in_sizes, int n_in,
                              void* d_out, int out_size, void* d_ws, size_t ws_size,
                              hipStream_t stream) {
  (void)in_sizes; (void)n_in; (void)out_size; (void)ws_size;
  const float* x       = (const float*)d_in[0];
  const float* q_w     = (const float*)d_in[1];
  const float* q_b     = (const float*)d_in[2];
  const float* kv_w    = (const float*)d_in[3];
  const float* kv_b    = (const float*)d_in[4];
  const float* gamma_q = (const float*)d_in[5];
  const float* gamma_k = (const float*)d_in[6];
  const float* out_w   = (const float*)d_in[7];
  float* out = (float*)d_out;

  char* ws = (char*)d_ws;
  __bf16* x_bf   = (__bf16*)(ws);                  // 16 MB [8192,1024]
  __bf16* qw_bf  = (__bf16*)(ws + (16ull << 20));  // 2 MB
  __bf16* kvw_bf = (__bf16*)(ws + (18ull << 20));  // 4 MB
  __bf16* ow_bf  = (__bf16*)(ws + (22ull << 20));  // 2 MB
  __bf16* q_bf   = (__bf16*)(ws + (24ull << 20));  // 16 MB [8192,1024] normalized q
  __bf16* k_bf   = (__bf16*)(ws + (40ull << 20));  // 16 MB [8192,1024] normalized k
  __bf16* vt_bf  = (__bf16*)(ws + (56ull << 20));  // 16 MB [B,H,D,S]
  __bf16* at_bf  = (__bf16*)(ws + (72ull << 20));  // 16 MB [8192,1024]

  cvt_bf16<<<8192, 256, 0, stream>>>(x, x_bf);
  cvt_bf16<<<1024, 256, 0, stream>>>(q_w, qw_bf);
  cvt_bf16<<<2048, 256, 0, stream>>>(kv_w, kvw_bf);
  cvt_bf16<<<1024, 256, 0, stream>>>(out_w, ow_bf);

  gemm_bt<2><<<dim3(8, 64), 256, 0, stream>>>(x_bf, qw_bf, q_b, gamma_q, q_bf, nullptr, nullptr,
                                              8192, 1024, 1024);
  gemm_bt<3><<<dim3(16, 64), 256, 0, stream>>>(x_bf, kvw_bf, kv_b, gamma_k, k_bf, nullptr, vt_bf,
                                               8192, 2048, 1024);

  attn_kernel<<<dim3(16, 64), 256, 0, stream>>>(q_bf, k_bf, vt_bf, at_bf);

  gemm_bt<1><<<dim3(8, 64), 256, 0, stream>>>(at_bf, ow_bf, nullptr, nullptr, nullptr, out, nullptr,
                                              8192, 1024, 1024);
}